// Round 2
// 693.548 us; speedup vs baseline: 1.1414x; 1.1414x over previous
//
#include <hip/hip_runtime.h>
#include <math.h>
#include <stdint.h>

namespace {

// ---------------- output layout (floats) ----------------
constexpr long OUT_ADJ = 0;                 // [8192,8192]
constexpr long OUT_Z   = 67108864;          // [8192,128]
constexpr long OUT_MU  = 68157440;
constexpr long OUT_LV  = 69206016;
constexpr long OUT_GMU = 70254592;
constexpr long OUT_GLV = 71303168;

// scratch carved out of d_out[OUT_ADJ] (dead until aat writes it at the end)
constexpr long P_F32OFF    = 0;             // 4 x [8192,256] fp32 split-K partials
constexpr long ADJBF_U16   = 16777216;      // u16 elem offset (float off 8388608), 64M elems
constexpr long Y1T_U16     = 83886080;      // [256,8192] bf16
constexpr long H1T_U16     = 85983232;      // [256,8192] bf16
constexpr long XBF_U16     = 88080384;      // [8192,512] bf16
constexpr long GBF_U16     = 92274688;      // [8192,256] bf16
constexpr long ZBF_U16     = 94371840;      // [8192,128] bf16
constexpr long W1T_U16     = 95420416;      // [256,512]  bf16 (W1^T)
constexpr long WCT_U16     = 95551488;      // [512,256]  bf16 (Wcat^T)
constexpr long WLT_U16     = 95682560;      // [128,128]  bf16 (Wl[0:128]^T)

// ---------------- workspace layout (floats) ----------------
constexpr long OFF_UBF   = 1048576;         // [8192,128] bf16 (u16; 524288 floats)
constexpr long OFF_STATS = 1572864;         // 640 floats
constexpr long OFF_M2    = 4194304;         // [8192,512] fp32

typedef short bf16x8 __attribute__((ext_vector_type(8)));   // 8 bf16 in 4 VGPRs
typedef float f32x4  __attribute__((ext_vector_type(4)));

__device__ __forceinline__ uint16_t f2bf(float f) {
    uint32_t u = __float_as_uint(f);
    return (uint16_t)((u + 0x7FFFu + ((u >> 16) & 1u)) >> 16);   // RNE
}

__device__ __forceinline__ void gload16(const void* g, void* lds) {
    // async global->LDS, 16B/lane; LDS dest = wave-uniform base + lane*16
    __builtin_amdgcn_global_load_lds(
        (__attribute__((address_space(1))) void*)(void*)g,
        (__attribute__((address_space(3))) void*)lds, 16, 0, 0);
}

// ---------------- fp32 -> bf16 bulk convert (8 elems/thread) ----------------
__global__ __launch_bounds__(256)
void cast_bf16(const float* __restrict__ in, uint16_t* __restrict__ out, long n8) {
    long i = (long)blockIdx.x * 256 + threadIdx.x;
    if (i >= n8) return;
    const float4* p = (const float4*)in + i * 2;
    float4 a = p[0], b = p[1];
    union { uint16_t u[8]; uint4 v; } r;
    r.u[0] = f2bf(a.x); r.u[1] = f2bf(a.y); r.u[2] = f2bf(a.z); r.u[3] = f2bf(a.w);
    r.u[4] = f2bf(b.x); r.u[5] = f2bf(b.y); r.u[6] = f2bf(b.z); r.u[7] = f2bf(b.w);
    *(uint4*)(out + i * 8) = r.v;
}

// ---------------- fused prep: cast x, transpose-cast W1/Wcat/Wl, zero stats ------
__global__ __launch_bounds__(256)
void prep_small(const float* __restrict__ x, const float* __restrict__ W1,
                const float* __restrict__ W2, const float* __restrict__ W3,
                const float* __restrict__ W4, const float* __restrict__ W5,
                const float* __restrict__ Wl,
                uint16_t* __restrict__ xbf, uint16_t* __restrict__ W1T,
                uint16_t* __restrict__ WcT, uint16_t* __restrict__ WlT,
                float* __restrict__ stats) {
    int b = blockIdx.x;
    int t = threadIdx.x;
    if (b < 2048) {                          // xbf: 8192*512 elems, 8/thread
        long i = (long)b * 256 + t;
        const float4* p = (const float4*)x + i * 2;
        float4 a = p[0], c = p[1];
        union { uint16_t u[8]; uint4 v; } r;
        r.u[0] = f2bf(a.x); r.u[1] = f2bf(a.y); r.u[2] = f2bf(a.z); r.u[3] = f2bf(a.w);
        r.u[4] = f2bf(c.x); r.u[5] = f2bf(c.y); r.u[6] = f2bf(c.z); r.u[7] = f2bf(c.w);
        *(uint4*)(xbf + i * 8) = r.v;
    } else if (b < 2048 + 512) {             // W1T[j*512+k] = W1[k*256+j]
        int id = (b - 2048) * 256 + t;
        int j = id >> 9, k = id & 511;
        W1T[id] = f2bf(W1[(long)k * 256 + j]);
    } else if (b < 2048 + 512 + 512) {       // WcT[c*256+k] = W_{q}[k*128+cc]
        int id = (b - 2048 - 512) * 256 + t;
        int c = id >> 8, k = id & 255;
        int q = c >> 7, cc = c & 127;
        const float* W = (q == 0) ? W2 : (q == 1) ? W3 : (q == 2) ? W4 : W5;
        WcT[id] = f2bf(W[(long)k * 128 + cc]);
    } else if (b < 2048 + 512 + 512 + 64) {  // WlT[j*128+k] = Wl[k*128+j], k<128
        int id = (b - 2048 - 1024) * 256 + t;
        int j = id >> 7, k = id & 127;
        WlT[id] = f2bf(Wl[(long)k * 128 + j]);
    } else {
        if (t < 256) stats[t] = 0.f;
    }
}

// ---------------- MFMA GEMM: C = A @ BT^T, 128x128 tile, 4 waves 2x2 ----------
// A [M,ldx] bf16 row-major, BT [Nout,ldx] bf16 row-major.
// MODE 0: write fp32 partial P (split-K via blockIdx.z)
// MODE 1: write bf16 TRANSPOSED O[col*8192+row] (full-K, ushort4 stores)
// MODE 2: write bf16 row-major O[row*Nout+col] with per-col bias (full-K)
template<int MODE>
__global__ __launch_bounds__(256)
void gemm_mfma_bt(const uint16_t* __restrict__ A, const uint16_t* __restrict__ BT,
                  float* __restrict__ P, uint16_t* __restrict__ O,
                  const float* __restrict__ bias,
                  int ldx, int Nout, int Ksplit) {
    __shared__ uint16_t sA[128 * 64];   // [row][chunk] 16B chunks, XOR-swizzled
    __shared__ uint16_t sB[128 * 64];
    const int t = threadIdx.x;
    const int l = t & 63, w = t >> 6;
    const int quad = l >> 4, l15 = l & 15;
    const long i0 = (long)blockIdx.x * 128;
    const long j0 = (long)blockIdx.y * 128;
    const int kbase = blockIdx.z * Ksplit;

    // staging: 4 wave-issues per tile; chunk swizzle c' = c ^ (row&7)
    const uint16_t* gA[4];
    const uint16_t* gB[4];
    int dstb[4];
    #pragma unroll
    for (int q = 0; q < 4; ++q) {
        int cid = (q * 4 + w) * 64 + l;
        int row = cid >> 3;
        int cg  = (cid & 7) ^ (row & 7);
        gA[q] = A  + (i0 + row) * (long)ldx + kbase + cg * 8;
        gB[q] = BT + (j0 + row) * (long)ldx + kbase + cg * 8;
        dstb[q] = (q * 4 + w) * 1024;   // wave-uniform LDS byte base
    }

    const int wm = w & 1, wn = w >> 1;
    int offA[2][4], offB[2][4];
    #pragma unroll
    for (int ks = 0; ks < 2; ++ks) {
        int g = ks * 4 + quad;
        #pragma unroll
        for (int i = 0; i < 4; ++i) {
            int m = 64 * wm + 16 * i + l15;
            offA[ks][i] = m * 64 + ((g ^ (m & 7)) * 8);
            int n = 64 * wn + 16 * i + l15;
            offB[ks][i] = n * 64 + ((g ^ (n & 7)) * 8);
        }
    }

    f32x4 acc[4][4];
    #pragma unroll
    for (int i = 0; i < 4; ++i)
        #pragma unroll
        for (int j = 0; j < 4; ++j)
            acc[i][j] = (f32x4){0.f, 0.f, 0.f, 0.f};

    char* sAb = (char*)&sA[0];
    char* sBb = (char*)&sB[0];
    for (int kt = 0; kt < Ksplit; kt += 64) {
        __syncthreads();                 // LDS free (prev compute done)
        #pragma unroll
        for (int q = 0; q < 4; ++q) {
            gload16(gA[q] + kt, sAb + dstb[q]);
            gload16(gB[q] + kt, sBb + dstb[q]);
        }
        __syncthreads();                 // drains vmcnt -> staging visible
        #pragma unroll
        for (int ks = 0; ks < 2; ++ks) {
            bf16x8 af[4], bfr[4];
            #pragma unroll
            for (int mi = 0; mi < 4; ++mi) af[mi]  = *(const bf16x8*)&sA[offA[ks][mi]];
            #pragma unroll
            for (int ni = 0; ni < 4; ++ni) bfr[ni] = *(const bf16x8*)&sB[offB[ks][ni]];
            #pragma unroll
            for (int mi = 0; mi < 4; ++mi)
                #pragma unroll
                for (int ni = 0; ni < 4; ++ni)
                    acc[mi][ni] = __builtin_amdgcn_mfma_f32_16x16x32_bf16(
                        af[mi], bfr[ni], acc[mi][ni], 0, 0, 0);
        }
    }

    if (MODE == 0) {
        float* Pz = P + (long)blockIdx.z * (8192l * Nout);
        #pragma unroll
        for (int mi = 0; mi < 4; ++mi) {
            #pragma unroll
            for (int ni = 0; ni < 4; ++ni) {
                f32x4 v = acc[mi][ni];
                long col = j0 + 64 * wn + 16 * ni + l15;
                #pragma unroll
                for (int r = 0; r < 4; ++r) {
                    long row = i0 + 64 * wm + 16 * mi + quad * 4 + r;
                    Pz[row * Nout + col] = v[r];
                }
            }
        }
    } else if (MODE == 1) {
        // transposed bf16: v[0..3] are 4 consecutive rows -> contiguous ushort4
        #pragma unroll
        for (int mi = 0; mi < 4; ++mi) {
            long rowb = i0 + 64 * wm + 16 * mi + quad * 4;
            #pragma unroll
            for (int ni = 0; ni < 4; ++ni) {
                f32x4 v = acc[mi][ni];
                long col = j0 + 64 * wn + 16 * ni + l15;
                union { uint16_t u[4]; uint2 q2; } r4;
                r4.u[0] = f2bf(v[0]); r4.u[1] = f2bf(v[1]);
                r4.u[2] = f2bf(v[2]); r4.u[3] = f2bf(v[3]);
                *(uint2*)&O[col * 8192 + rowb] = r4.q2;
            }
        }
    } else {
        // row-major bf16 + bias
        #pragma unroll
        for (int mi = 0; mi < 4; ++mi) {
            long rowb = i0 + 64 * wm + 16 * mi + quad * 4;
            #pragma unroll
            for (int ni = 0; ni < 4; ++ni) {
                f32x4 v = acc[mi][ni];
                long col = j0 + 64 * wn + 16 * ni + l15;
                float bv = bias[col];
                #pragma unroll
                for (int r = 0; r < 4; ++r)
                    O[(rowb + r) * Nout + col] = f2bf(v[r] + bv);
            }
        }
    }
}

// ---------------- reduce NSUM partials, optional relu, transpose, cast bf16 ----
template<int NSUM, bool RELU>
__global__ __launch_bounds__(256)
void reduce_transpose_cast(const float* __restrict__ P, int M, int Ncols, long stride,
                           uint16_t* __restrict__ OT) {
    __shared__ float tile[64][65];
    long r0 = (long)blockIdx.x * 64;
    int  c0 = blockIdx.y * 64;
    int t = threadIdx.x;
    #pragma unroll
    for (int p = 0; p < 16; ++p) {
        int e = p * 256 + t;
        int r = e >> 6, c = e & 63;
        long idx = (r0 + r) * Ncols + c0 + c;
        float s = 0.f;
        #pragma unroll
        for (int q = 0; q < NSUM; ++q) s += P[idx + q * stride];
        if (RELU) s = fmaxf(s, 0.f);
        tile[r][c] = s;
    }
    __syncthreads();
    #pragma unroll
    for (int p = 0; p < 16; ++p) {
        int e = p * 256 + t;
        int c = e >> 6, r = e & 63;
        OT[(long)(c0 + c) * M + r0 + r] = f2bf(tile[r][c]);
    }
}

// sum 4 split-K partials -> bf16 row-major G (8 elems/thread)
__global__ __launch_bounds__(256)
void reduce4_bf16(const float4* __restrict__ P, uint16_t* __restrict__ G) {
    long i = (long)blockIdx.x * 256 + threadIdx.x;   // < 262144
    long b = i * 2;
    float4 s0 = {0.f,0.f,0.f,0.f}, s1 = {0.f,0.f,0.f,0.f};
    #pragma unroll
    for (int q = 0; q < 4; ++q) {
        float4 a = P[b + q * 524288];
        float4 c = P[b + 1 + q * 524288];
        s0.x += a.x; s0.y += a.y; s0.z += a.z; s0.w += a.w;
        s1.x += c.x; s1.y += c.y; s1.z += c.z; s1.w += c.w;
    }
    union { uint16_t u[8]; uint4 v; } r;
    r.u[0] = f2bf(s0.x); r.u[1] = f2bf(s0.y); r.u[2] = f2bf(s0.z); r.u[3] = f2bf(s0.w);
    r.u[4] = f2bf(s1.x); r.u[5] = f2bf(s1.y); r.u[6] = f2bf(s1.z); r.u[7] = f2bf(s1.w);
    *(uint4*)(G + i * 8) = r.v;
}

// ---------------- group evidence ----------------
__global__ __launch_bounds__(128)
void group_reduce(const float* __restrict__ M2, float* __restrict__ stats) {
    int j = threadIdx.x;
    long base = (long)blockIdx.x * 32;
    float accP = 0.f, accS = 0.f;
    for (int r = 0; r < 32; ++r) {
        long i = base + r;
        float cmu = M2[i * 512 + 256 + j];
        float clv = M2[i * 512 + 384 + j];
        float var = expf(clv);
        if (var == 0.f) var = 1e-6f;
        float inv = 1.f / var;
        accP += inv;
        accS += cmu * inv;
    }
    atomicAdd(&stats[j], accP);
    atomicAdd(&stats[128 + j], accS);
}

__global__ __launch_bounds__(128)
void finalize_k(float* __restrict__ stats, const float* __restrict__ eps_group,
                const float* __restrict__ Wl, const float* __restrict__ bl) {
    __shared__ float cl[128];
    int j = threadIdx.x;
    float prec = stats[j];
    float s    = stats[128 + j];
    float gvar = 1.f / prec;
    float gmu  = gvar * s;
    float gv   = gvar; if (gv == 0.f) gv = 1e-6f;
    float glv  = logf(gv);
    stats[256 + j] = gmu;
    stats[384 + j] = glv;
    cl[j] = gmu + expf(0.5f * glv) * eps_group[j];
    __syncthreads();
    float c2 = bl[j];
    for (int k = 0; k < 128; ++k)
        c2 = fmaf(cl[k], Wl[(128 + k) * 128 + j], c2);
    stats[512 + j] = c2;
}

__global__ __launch_bounds__(256)
void epilogue_z(const float* __restrict__ M2, const float* __restrict__ eps_z,
                const float* __restrict__ stats, float* __restrict__ out,
                uint16_t* __restrict__ zbf) {
    long id = (long)blockIdx.x * 256 + threadIdx.x;
    long i = id >> 7;
    int  j = (int)(id & 127);
    float mu = M2[i * 512 + j];
    float lv = M2[i * 512 + 128 + j];
    float z  = eps_z[id] * expf(lv) + mu;
    out[OUT_Z   + id] = z;
    out[OUT_MU  + id] = mu;
    out[OUT_LV  + id] = lv;
    out[OUT_GMU + id] = stats[256 + j];
    out[OUT_GLV + id] = stats[384 + j];
    zbf[id] = f2bf(z);
}

// ---------------- adj_recon = U @ U^T via MFMA, U [8192,128] bf16 ----------------
__global__ __launch_bounds__(256)
void aat_mfma(const uint16_t* __restrict__ U, float* __restrict__ C) {
    __shared__ uint16_t sA[128 * 128];   // 32 KB, chunk swizzle c' = c ^ (row&15)
    __shared__ uint16_t sB[128 * 128];
    const int t = threadIdx.x;
    const int l = t & 63, w = t >> 6;
    const int quad = l >> 4, l15 = l & 15;
    const long i0 = (long)blockIdx.x * 128;
    const long j0 = (long)blockIdx.y * 128;

    #pragma unroll
    for (int q = 0; q < 8; ++q) {
        int cid = (q * 4 + w) * 64 + l;
        int row = cid >> 4;
        int cg  = (cid & 15) ^ (row & 15);
        int dstb = (q * 4 + w) * 1024;
        gload16(U + (i0 + row) * 128 + cg * 8, (char*)&sA[0] + dstb);
        gload16(U + (j0 + row) * 128 + cg * 8, (char*)&sB[0] + dstb);
    }

    f32x4 acc[4][4];
    #pragma unroll
    for (int i = 0; i < 4; ++i)
        #pragma unroll
        for (int j = 0; j < 4; ++j)
            acc[i][j] = (f32x4){0.f, 0.f, 0.f, 0.f};

    __syncthreads();   // drains vmcnt -> LDS ready

    const int wm = w & 1, wn = w >> 1;
    #pragma unroll
    for (int ks = 0; ks < 4; ++ks) {
        int g = ks * 4 + quad;
        bf16x8 af[4], bfr[4];
        #pragma unroll
        for (int mi = 0; mi < 4; ++mi) {
            int m = 64 * wm + 16 * mi + l15;
            af[mi] = *(const bf16x8*)&sA[m * 128 + ((g ^ (m & 15)) * 8)];
        }
        #pragma unroll
        for (int ni = 0; ni < 4; ++ni) {
            int n = 64 * wn + 16 * ni + l15;
            bfr[ni] = *(const bf16x8*)&sB[n * 128 + ((g ^ (n & 15)) * 8)];
        }
        #pragma unroll
        for (int mi = 0; mi < 4; ++mi)
            #pragma unroll
            for (int ni = 0; ni < 4; ++ni)
                acc[mi][ni] = __builtin_amdgcn_mfma_f32_16x16x32_bf16(
                    af[mi], bfr[ni], acc[mi][ni], 0, 0, 0);
    }

    #pragma unroll
    for (int mi = 0; mi < 4; ++mi) {
        #pragma unroll
        for (int ni = 0; ni < 4; ++ni) {
            f32x4 v = acc[mi][ni];
            long col = j0 + 64 * wn + 16 * ni + l15;
            #pragma unroll
            for (int r = 0; r < 4; ++r) {
                long row = i0 + 64 * wm + 16 * mi + quad * 4 + r;
                C[row * 8192 + col] = v[r];
            }
        }
    }
}

} // namespace

extern "C" void kernel_launch(void* const* d_in, const int* in_sizes, int n_in,
                              void* d_out, int out_size, void* d_ws, size_t ws_size,
                              hipStream_t stream) {
    (void)in_sizes; (void)n_in; (void)out_size; (void)ws_size;
    const float* x     = (const float*)d_in[0];
    const float* adj   = (const float*)d_in[1];
    const float* W1    = (const float*)d_in[2];
    const float* W2    = (const float*)d_in[3];
    const float* W3    = (const float*)d_in[4];
    const float* W4    = (const float*)d_in[5];
    const float* W5    = (const float*)d_in[6];
    const float* Wl    = (const float*)d_in[7];
    const float* bl    = (const float*)d_in[8];
    const float* eps_z = (const float*)d_in[9];
    const float* eps_g = (const float*)d_in[10];
    // d_in[11] = batch: all zeros -> single group (folded into reduction)

    float*    out  = (float*)d_out;
    uint16_t* outu = (uint16_t*)d_out;
    float*    ws   = (float*)d_ws;

    // scratch inside d_out[OUT_ADJ] (all dead before aat overwrites it)
    float*    P     = out + P_F32OFF;
    uint16_t* adjbf = outu + ADJBF_U16;
    uint16_t* Y1T   = outu + Y1T_U16;
    uint16_t* h1T   = outu + H1T_U16;
    uint16_t* xbf   = outu + XBF_U16;
    uint16_t* Gbf   = outu + GBF_U16;
    uint16_t* zbf   = outu + ZBF_U16;
    uint16_t* W1T   = outu + W1T_U16;
    uint16_t* WcT   = outu + WCT_U16;
    uint16_t* WlT   = outu + WLT_U16;

    uint16_t* Ubf = (uint16_t*)(ws + OFF_UBF);
    float*    st  = ws + OFF_STATS;
    float*    M2  = ws + OFF_M2;

    // adj -> bf16 (384 MB traffic); fused prep for everything small
    cast_bf16<<<32768, 256, 0, stream>>>(adj, adjbf, 8388608);
    prep_small<<<3137, 256, 0, stream>>>(x, W1, W2, W3, W4, W5, Wl,
                                         xbf, W1T, WcT, WlT, st);

    // Y1^T = (x @ W1)^T, bf16 direct (MFMA, transposed epilogue)
    gemm_mfma_bt<1><<<dim3(64, 2, 1), 256, 0, stream>>>(
        xbf, W1T, nullptr, Y1T, nullptr, 512, 256, 512);

    // h1 = relu(adj @ Y1): MFMA split-K=4, then reduce+relu+transpose -> h1T bf16
    gemm_mfma_bt<0><<<dim3(64, 2, 4), 256, 0, stream>>>(
        adjbf, Y1T, P, nullptr, nullptr, 8192, 256, 2048);
    reduce_transpose_cast<4, true><<<dim3(128, 4), 256, 0, stream>>>(P, 8192, 256, 2097152, h1T);

    // G = adj @ h1: MFMA split-K=4, then reduce -> Gbf bf16
    gemm_mfma_bt<0><<<dim3(64, 2, 4), 256, 0, stream>>>(
        adjbf, h1T, P, nullptr, nullptr, 8192, 256, 2048);
    reduce4_bf16<<<1024, 256, 0, stream>>>((const float4*)P, Gbf);

    // M2 = G @ Wcat (MFMA, fp32 out direct -- no reduce pass)
    gemm_mfma_bt<0><<<dim3(64, 4, 1), 256, 0, stream>>>(
        Gbf, WcT, M2, nullptr, nullptr, 256, 512, 256);

    group_reduce<<<256, 128, 0, stream>>>(M2, st);
    finalize_k<<<1, 128, 0, stream>>>(st, eps_g, Wl, bl);
    epilogue_z<<<4096, 256, 0, stream>>>(M2, eps_z, st, out, zbf);

    // Ubf = bf16(z @ Wl[0:128] + c2)  (MFMA, bias+bf16 epilogue, no cast pass)
    gemm_mfma_bt<2><<<dim3(64, 1, 1), 256, 0, stream>>>(
        zbf, WlT, nullptr, Ubf, st + 512, 128, 128, 128);

    // adj_recon = U @ U^T (MFMA, write-bound 256 MB)
    aat_mfma<<<dim3(64, 64), 256, 0, stream>>>(Ubf, out);
}